// Round 2
// baseline (817.793 us; speedup 1.0000x reference)
//
#include <hip/hip_runtime.h>
#include <math.h>

#define B_  1024
#define S_  256
#define H_  512
#define E_  64
#define R_  32
#define L_  9
#define EPS_ 1e-6f
#define TB  16   // b-tile for MLP kernel

// ---------------------------------------------------------------------------
// Kernel 1: fused 2-layer MLP for the 4 live modules (m=0 -> e[0], m=1..3 -> r[0..2])
// h = tanh(x @ W1 + b1); out = h @ W2 + b2
// grid (B/TB, 4), block 256
// ---------------------------------------------------------------------------
__global__ __launch_bounds__(256) void mlp_kernel(
    const float* __restrict__ x,     // [B,S]
    const float* __restrict__ eW1, const float* __restrict__ eb1,
    const float* __restrict__ eW2, const float* __restrict__ eb2,
    const float* __restrict__ rW1, const float* __restrict__ rb1,
    const float* __restrict__ rW2, const float* __restrict__ rb2,
    float* __restrict__ e0_out,      // [B,E]
    float* __restrict__ r_out)       // [3,B,R]
{
    __shared__ float xs[TB][S_];     // 16 KB
    __shared__ float hs[TB][H_];     // 32 KB
    const int t  = threadIdx.x;
    const int b0 = blockIdx.x * TB;
    const int m  = blockIdx.y;       // 0 = e0, 1..3 = r0..r2

    #pragma unroll
    for (int i = 0; i < TB; ++i)
        xs[i][t] = x[(size_t)(b0 + i) * S_ + t];
    __syncthreads();

    const float* W1 = (m == 0) ? eW1 : (rW1 + (size_t)(m - 1) * S_ * H_);
    const float* b1 = (m == 0) ? eb1 : (rb1 + (size_t)(m - 1) * H_);

    float acc0[TB], acc1[TB];
    #pragma unroll
    for (int bb = 0; bb < TB; ++bb) { acc0[bb] = 0.0f; acc1[bb] = 0.0f; }

    for (int s = 0; s < S_; ++s) {
        float w0 = W1[(size_t)s * H_ + t];
        float w1 = W1[(size_t)s * H_ + t + 256];
        #pragma unroll
        for (int bb = 0; bb < TB; ++bb) {
            float xv = xs[bb][s];
            acc0[bb] = fmaf(xv, w0, acc0[bb]);
            acc1[bb] = fmaf(xv, w1, acc1[bb]);
        }
    }
    float bias0 = b1[t], bias1 = b1[t + 256];
    #pragma unroll
    for (int bb = 0; bb < TB; ++bb) {
        hs[bb][t]       = tanhf(acc0[bb] + bias0);
        hs[bb][t + 256] = tanhf(acc1[bb] + bias1);
    }
    __syncthreads();

    if (m == 0) {
        const float* W2 = eW2;
        const float* b2 = eb2;
        int o  = t & 63;
        int bq = t >> 6;                     // 0..3
        #pragma unroll
        for (int i = 0; i < TB / 4; ++i) {
            int bb = bq + i * 4;
            float acc = b2[o];
            for (int j = 0; j < H_; ++j)
                acc = fmaf(hs[bb][j], W2[(size_t)j * E_ + o], acc);
            e0_out[(size_t)(b0 + bb) * E_ + o] = acc;
        }
    } else {
        const float* W2 = rW2 + (size_t)(m - 1) * H_ * R_;
        const float* b2 = rb2 + (size_t)(m - 1) * R_;
        int o  = t & 31;
        int bq = t >> 5;                     // 0..7
        #pragma unroll
        for (int i = 0; i < TB / 8; ++i) {
            int bb = bq + i * 8;
            float acc = b2[o];
            for (int j = 0; j < H_; ++j)
                acc = fmaf(hs[bb][j], W2[(size_t)j * R_ + o], acc);
            r_out[((size_t)(m - 1) * B_ + (b0 + bb)) * R_ + o] = acc;
        }
    }
}

// ---------------------------------------------------------------------------
// Kernel A: build M matrices. M[b,k,e,f] = sum_r r_k[b,r] * tpr[b,e,r,f]
// No cross-e reduction -> (b,e) rows fully parallel, no big LDS, low VGPR.
// grid (B, 4), block 256: each block does 16 e-rows; thread = (e_row, f4).
// Traffic: 512 MB read + 48 MB write, streaming.
// ---------------------------------------------------------------------------
__global__ __launch_bounds__(256) void build_m_kernel(
    const float* __restrict__ tpr,   // [B,E,R,E]
    const float* __restrict__ rws,   // [3,B,R]
    float* __restrict__ Mws)         // [B,3,E,E]
{
    __shared__ float rsh[3][R_];
    const int t = threadIdx.x;
    const int b = blockIdx.x;
    const int ey = blockIdx.y;       // 0..3

    if (t < 96) { int k = t >> 5, j = t & 31; rsh[k][j] = rws[((size_t)k * B_ + b) * R_ + j]; }
    __syncthreads();

    const int f4 = t & 15;           // float4 index within the 64-float f row
    const int e  = (t >> 4) + 16 * ey;

    const float4* row = (const float4*)(tpr + (size_t)b * E_ * R_ * E_) + (size_t)e * 512;

    float4 a0 = {0, 0, 0, 0}, a1 = {0, 0, 0, 0}, a2 = {0, 0, 0, 0};
    #pragma unroll 8
    for (int r = 0; r < R_; ++r) {
        float4 v = row[r * 16 + f4];
        float w0 = rsh[0][r], w1 = rsh[1][r], w2 = rsh[2][r];
        a0.x = fmaf(w0, v.x, a0.x); a0.y = fmaf(w0, v.y, a0.y);
        a0.z = fmaf(w0, v.z, a0.z); a0.w = fmaf(w0, v.w, a0.w);
        a1.x = fmaf(w1, v.x, a1.x); a1.y = fmaf(w1, v.y, a1.y);
        a1.z = fmaf(w1, v.z, a1.z); a1.w = fmaf(w1, v.w, a1.w);
        a2.x = fmaf(w2, v.x, a2.x); a2.y = fmaf(w2, v.y, a2.y);
        a2.z = fmaf(w2, v.z, a2.z); a2.w = fmaf(w2, v.w, a2.w);
    }

    float4* M4 = (float4*)(Mws + (size_t)b * 3 * E_ * E_);
    M4[(0 * E_ + e) * 16 + f4] = a0;
    M4[(1 * E_ + e) * 16 + f4] = a1;
    M4[(2 * E_ + e) * 16 + f4] = a2;
}

// ---------------------------------------------------------------------------
// Kernel B: sequential LN chain per b, from the materialized M.
// All 256 threads preload M[b] (48 KB) into LDS coalesced; wave 0 runs chain.
// grid B, block 256.
// ---------------------------------------------------------------------------
__global__ __launch_bounds__(256) void chain_kernel(
    const float* __restrict__ Mws,   // [B,3,E,E]
    const float* __restrict__ e0,    // [B,E]
    const float* __restrict__ ln_g,  // [3,E]
    const float* __restrict__ ln_b,  // [3,E]
    const float* __restrict__ Z,     // [E,L]
    float* __restrict__ out)         // [B,L]
{
    __shared__ __align__(16) float M[3][E_][E_];   // 48 KB
    __shared__ float xcur[E_];
    __shared__ float ssum_sh[E_];

    const int t = threadIdx.x;
    const int b = blockIdx.x;

    // preload M[b]: 3072 float4, 12 per thread, coalesced
    const float4* src = (const float4*)(Mws + (size_t)b * 3 * E_ * E_);
    float4* dst = (float4*)&M[0][0][0];
    #pragma unroll
    for (int i = 0; i < 12; ++i)
        dst[t + 256 * i] = src[t + 256 * i];

    if (t < E_) xcur[t] = e0[(size_t)b * E_ + t];
    __syncthreads();

    float ssum = 0.0f;
    for (int k = 0; k < 3; ++k) {
        float iv = 0.0f;
        if (t < E_) {
            const int f = t;
            float acc = 0.0f;
            #pragma unroll 8
            for (int e = 0; e < E_; ++e)
                acc = fmaf(xcur[e], M[k][e][f], acc);
            float s = acc;
            #pragma unroll
            for (int off = 32; off >= 1; off >>= 1) s += __shfl_xor(s, off, 64);
            float mu = s * (1.0f / 64.0f);
            float d = acc - mu;
            float vs = d * d;
            #pragma unroll
            for (int off = 32; off >= 1; off >>= 1) vs += __shfl_xor(vs, off, 64);
            float var = vs * (1.0f / 64.0f);
            iv = ln_g[k * E_ + f] * d * rsqrtf(var + EPS_) + ln_b[k * E_ + f];
            ssum += iv;
        }
        __syncthreads();
        if (t < E_) xcur[t] = iv;
        __syncthreads();
    }

    if (t < E_) ssum_sh[t] = ssum;
    __syncthreads();

    if (t < L_) {
        float acc = 0.0f;
        #pragma unroll
        for (int f = 0; f < E_; ++f)
            acc = fmaf(ssum_sh[f], Z[f * L_ + t], acc);
        out[(size_t)b * L_ + t] = acc;
    }
}

// ---------------------------------------------------------------------------
extern "C" void kernel_launch(void* const* d_in, const int* in_sizes, int n_in,
                              void* d_out, int out_size, void* d_ws, size_t ws_size,
                              hipStream_t stream) {
    const float* x    = (const float*)d_in[0];
    const float* tpr  = (const float*)d_in[1];
    const float* eW1  = (const float*)d_in[2];
    const float* eb1  = (const float*)d_in[3];
    const float* eW2  = (const float*)d_in[4];
    const float* eb2  = (const float*)d_in[5];
    const float* rW1  = (const float*)d_in[6];
    const float* rb1  = (const float*)d_in[7];
    const float* rW2  = (const float*)d_in[8];
    const float* rb2  = (const float*)d_in[9];
    const float* ln_g = (const float*)d_in[10];
    const float* ln_b = (const float*)d_in[11];
    const float* Z    = (const float*)d_in[12];
    float* out = (float*)d_out;

    float* e0_ws = (float*)d_ws;                       // B*E floats
    float* r_ws  = e0_ws + (size_t)B_ * E_;            // 3*B*R floats
    float* M_ws  = r_ws + (size_t)3 * B_ * R_;         // B*3*E*E floats (50.3 MB)

    dim3 g1(B_ / TB, 4);
    mlp_kernel<<<g1, 256, 0, stream>>>(x, eW1, eb1, eW2, eb2,
                                       rW1, rb1, rW2, rb2, e0_ws, r_ws);
    dim3 g2(B_, 4);
    build_m_kernel<<<g2, 256, 0, stream>>>(tpr, r_ws, M_ws);
    chain_kernel<<<B_, 256, 0, stream>>>(M_ws, e0_ws, ln_g, ln_b, Z, out);
}

// Round 3
// 756.508 us; speedup vs baseline: 1.0810x; 1.0810x over previous
//
#include <hip/hip_runtime.h>
#include <math.h>

#define B_  1024
#define S_  256
#define H_  512
#define E_  64
#define R_  32
#define L_  9
#define EPS_ 1e-6f
#define TB  8    // b-tile for MLP kernel (2 blocks/CU)

// ---------------------------------------------------------------------------
// Kernel 1: fused 2-layer MLP for the 4 live modules (m=0 -> e[0], m=1..3 -> r[0..2])
// h = tanh(x @ W1 + b1); out = h @ W2 + b2
// grid (B/TB, 4), block 256
// ---------------------------------------------------------------------------
__global__ __launch_bounds__(256) void mlp_kernel(
    const float* __restrict__ x,     // [B,S]
    const float* __restrict__ eW1, const float* __restrict__ eb1,
    const float* __restrict__ eW2, const float* __restrict__ eb2,
    const float* __restrict__ rW1, const float* __restrict__ rb1,
    const float* __restrict__ rW2, const float* __restrict__ rb2,
    float* __restrict__ e0_out,      // [B,E]
    float* __restrict__ r_out)       // [3,B,R]
{
    __shared__ float xs[TB][S_];     // 8 KB
    __shared__ float hs[TB][H_];     // 16 KB
    const int t  = threadIdx.x;
    const int b0 = blockIdx.x * TB;
    const int m  = blockIdx.y;       // 0 = e0, 1..3 = r0..r2

    #pragma unroll
    for (int i = 0; i < TB; ++i)
        xs[i][t] = x[(size_t)(b0 + i) * S_ + t];
    __syncthreads();

    const float* W1 = (m == 0) ? eW1 : (rW1 + (size_t)(m - 1) * S_ * H_);
    const float* b1 = (m == 0) ? eb1 : (rb1 + (size_t)(m - 1) * H_);

    float acc0[TB], acc1[TB];
    #pragma unroll
    for (int bb = 0; bb < TB; ++bb) { acc0[bb] = 0.0f; acc1[bb] = 0.0f; }

    for (int s = 0; s < S_; ++s) {
        float w0 = W1[(size_t)s * H_ + t];
        float w1 = W1[(size_t)s * H_ + t + 256];
        #pragma unroll
        for (int bb = 0; bb < TB; ++bb) {
            float xv = xs[bb][s];
            acc0[bb] = fmaf(xv, w0, acc0[bb]);
            acc1[bb] = fmaf(xv, w1, acc1[bb]);
        }
    }
    float bias0 = b1[t], bias1 = b1[t + 256];
    #pragma unroll
    for (int bb = 0; bb < TB; ++bb) {
        hs[bb][t]       = tanhf(acc0[bb] + bias0);
        hs[bb][t + 256] = tanhf(acc1[bb] + bias1);
    }
    __syncthreads();

    if (m == 0) {
        const float* W2 = eW2;
        const float* b2 = eb2;
        int o  = t & 63;
        int bq = t >> 6;                     // 0..3
        #pragma unroll
        for (int i = 0; i < TB / 4; ++i) {
            int bb = bq + i * 4;
            float acc = b2[o];
            for (int j = 0; j < H_; ++j)
                acc = fmaf(hs[bb][j], W2[(size_t)j * E_ + o], acc);
            e0_out[(size_t)(b0 + bb) * E_ + o] = acc;
        }
    } else {
        const float* W2 = rW2 + (size_t)(m - 1) * H_ * R_;
        const float* b2 = rb2 + (size_t)(m - 1) * R_;
        int o  = t & 31;
        int bb = t >> 5;                     // 0..7 == TB
        float acc = b2[o];
        for (int j = 0; j < H_; ++j)
            acc = fmaf(hs[bb][j], W2[(size_t)j * R_ + o], acc);
        r_out[((size_t)(m - 1) * B_ + (b0 + bb)) * R_ + o] = acc;
    }
}

// ---------------------------------------------------------------------------
// Kernel 2: fused per-b TPR chain, single pass over tpr[b].
//  Phase M: stream tpr[b] (512 KB) once:
//    - t0 partial[f] += e0[e] * (sum_r r0[r]*tpr[b,e,r,f])   (registers -> red)
//    - M1[e][f], M2[e][f] into LDS (32 KB)
//  Phase S: wave 0 only (no barriers inside): LN chain + Z projection.
// LDS ~37 KB -> 4 blocks/CU, matching grid 1024 = 4 * 256 CUs.
// ---------------------------------------------------------------------------
__global__ __launch_bounds__(256) void tpr_kernel(
    const float* __restrict__ tpr,   // [B,E,R,E]
    const float* __restrict__ e0,    // [B,E]
    const float* __restrict__ rws,   // [3,B,R]
    const float* __restrict__ ln_g,  // [3,E]
    const float* __restrict__ ln_b,  // [3,E]
    const float* __restrict__ Z,     // [E,L]
    float* __restrict__ out)         // [B,L]
{
    __shared__ __align__(16) float M[2][E_][E_];     // 32 KB  (M1, M2)
    __shared__ __align__(16) float red[16][E_];      // 4 KB   (t0 partials)
    __shared__ float xcur[E_];
    __shared__ float ssum_sh[E_];
    __shared__ float rsh[3][R_];
    __shared__ float e0sh[E_];

    const int t = threadIdx.x;
    const int b = blockIdx.x;

    if (t < 96) { int k = t >> 5, j = t & 31; rsh[k][j] = rws[((size_t)k * B_ + b) * R_ + j]; }
    if (t < E_) e0sh[t] = e0[(size_t)b * E_ + t];
    __syncthreads();

    // ---- Phase M: stream tpr[b] once (float4) ----
    const float4* tpr4 = (const float4*)(tpr + (size_t)b * E_ * R_ * E_);
    const int f4 = t & 15;       // float4 index within the 64-float f row
    const int eg = t >> 4;       // 0..15

    float4 t0p = {0, 0, 0, 0};
    #pragma unroll
    for (int ep = 0; ep < 4; ++ep) {
        int e = eg + 16 * ep;
        float4 a0 = {0, 0, 0, 0}, a1 = {0, 0, 0, 0}, a2 = {0, 0, 0, 0};
        #pragma unroll 8
        for (int r = 0; r < R_; ++r) {
            float4 v = tpr4[e * 512 + r * 16 + f4];
            float w0 = rsh[0][r], w1 = rsh[1][r], w2 = rsh[2][r];
            a0.x = fmaf(w0, v.x, a0.x); a0.y = fmaf(w0, v.y, a0.y);
            a0.z = fmaf(w0, v.z, a0.z); a0.w = fmaf(w0, v.w, a0.w);
            a1.x = fmaf(w1, v.x, a1.x); a1.y = fmaf(w1, v.y, a1.y);
            a1.z = fmaf(w1, v.z, a1.z); a1.w = fmaf(w1, v.w, a1.w);
            a2.x = fmaf(w2, v.x, a2.x); a2.y = fmaf(w2, v.y, a2.y);
            a2.z = fmaf(w2, v.z, a2.z); a2.w = fmaf(w2, v.w, a2.w);
        }
        ((float4*)&M[0][e][0])[f4] = a1;
        ((float4*)&M[1][e][0])[f4] = a2;
        float ev = e0sh[e];
        t0p.x = fmaf(ev, a0.x, t0p.x); t0p.y = fmaf(ev, a0.y, t0p.y);
        t0p.z = fmaf(ev, a0.z, t0p.z); t0p.w = fmaf(ev, a0.w, t0p.w);
    }
    ((float4*)&red[eg][0])[f4] = t0p;
    __syncthreads();

    // ---- Phase S: wave 0 only, no barriers (in-wave LDS ordering suffices) ----
    if (t < E_) {
        const int f = t;
        // t0[f] = sum over the 16 e-groups
        float acc = 0.0f;
        #pragma unroll
        for (int g = 0; g < 16; ++g) acc += red[g][f];

        float ssum = 0.0f;
        #pragma unroll
        for (int k = 0; k < 3; ++k) {
            float s = acc;
            #pragma unroll
            for (int off = 32; off >= 1; off >>= 1) s += __shfl_xor(s, off, 64);
            float mu = s * (1.0f / 64.0f);
            float d = acc - mu;
            float vs = d * d;
            #pragma unroll
            for (int off = 32; off >= 1; off >>= 1) vs += __shfl_xor(vs, off, 64);
            float var = vs * (1.0f / 64.0f);
            float iv = ln_g[k * E_ + f] * d * rsqrtf(var + EPS_) + ln_b[k * E_ + f];
            ssum += iv;
            if (k < 2) {
                xcur[f] = iv;
                float na = 0.0f;
                #pragma unroll 8
                for (int e = 0; e < E_; ++e)
                    na = fmaf(xcur[e], M[k][e][f], na);
                acc = na;
            }
        }
        ssum_sh[f] = ssum;

        if (t < L_) {
            float o = 0.0f;
            #pragma unroll
            for (int f2 = 0; f2 < E_; ++f2)
                o = fmaf(ssum_sh[f2], Z[f2 * L_ + t], o);
            out[(size_t)b * L_ + t] = o;
        }
    }
}

// ---------------------------------------------------------------------------
extern "C" void kernel_launch(void* const* d_in, const int* in_sizes, int n_in,
                              void* d_out, int out_size, void* d_ws, size_t ws_size,
                              hipStream_t stream) {
    const float* x    = (const float*)d_in[0];
    const float* tpr  = (const float*)d_in[1];
    const float* eW1  = (const float*)d_in[2];
    const float* eb1  = (const float*)d_in[3];
    const float* eW2  = (const float*)d_in[4];
    const float* eb2  = (const float*)d_in[5];
    const float* rW1  = (const float*)d_in[6];
    const float* rb1  = (const float*)d_in[7];
    const float* rW2  = (const float*)d_in[8];
    const float* rb2  = (const float*)d_in[9];
    const float* ln_g = (const float*)d_in[10];
    const float* ln_b = (const float*)d_in[11];
    const float* Z    = (const float*)d_in[12];
    float* out = (float*)d_out;

    float* e0_ws = (float*)d_ws;             // B*E floats
    float* r_ws  = e0_ws + (size_t)B_ * E_;  // 3*B*R floats

    dim3 g1(B_ / TB, 4);
    mlp_kernel<<<g1, 256, 0, stream>>>(x, eW1, eb1, eW2, eb2,
                                       rW1, rb1, rW2, rb2, e0_ws, r_ws);
    tpr_kernel<<<B_, 256, 0, stream>>>(tpr, e0_ws, r_ws, ln_g, ln_b, Z, out);
}

// Round 5
// 737.273 us; speedup vs baseline: 1.1092x; 1.0261x over previous
//
#include <hip/hip_runtime.h>
#include <math.h>

#define B_  1024
#define S_  256
#define H_  512
#define E_  64
#define R_  32
#define L_  9
#define EPS_ 1e-6f
#define TB  8    // b-tile for MLP kernel (2 blocks/CU)

typedef float nfloat4 __attribute__((ext_vector_type(4)));   // nontemporal-load-compatible float4

// ---------------------------------------------------------------------------
// Kernel 1: fused 2-layer MLP for the 4 live modules (m=0 -> e[0], m=1..3 -> r[0..2])
// h = tanh(x @ W1 + b1); out = h @ W2 + b2
// grid (B/TB, 4), block 256
// ---------------------------------------------------------------------------
__global__ __launch_bounds__(256) void mlp_kernel(
    const float* __restrict__ x,     // [B,S]
    const float* __restrict__ eW1, const float* __restrict__ eb1,
    const float* __restrict__ eW2, const float* __restrict__ eb2,
    const float* __restrict__ rW1, const float* __restrict__ rb1,
    const float* __restrict__ rW2, const float* __restrict__ rb2,
    float* __restrict__ e0_out,      // [B,E]
    float* __restrict__ r_out)       // [3,B,R]
{
    __shared__ __align__(16) float xs[TB][S_];   // 8 KB
    __shared__ float hs[TB][H_];                 // 16 KB
    const int t  = threadIdx.x;
    const int b0 = blockIdx.x * TB;
    const int m  = blockIdx.y;       // 0 = e0, 1..3 = r0..r2

    // float4 staging of the x tile: TB*S_/4 = 512 float4, 2 per thread
    {
        const float4* x4 = (const float4*)(x + (size_t)b0 * S_);
        float4* xs4 = (float4*)&xs[0][0];
        xs4[t]       = x4[t];
        xs4[t + 256] = x4[t + 256];
    }
    __syncthreads();

    const float* W1 = (m == 0) ? eW1 : (rW1 + (size_t)(m - 1) * S_ * H_);
    const float* b1 = (m == 0) ? eb1 : (rb1 + (size_t)(m - 1) * H_);

    float acc0[TB], acc1[TB];
    #pragma unroll
    for (int bb = 0; bb < TB; ++bb) { acc0[bb] = 0.0f; acc1[bb] = 0.0f; }

    for (int s = 0; s < S_; ++s) {
        float w0 = W1[(size_t)s * H_ + t];
        float w1 = W1[(size_t)s * H_ + t + 256];
        #pragma unroll
        for (int bb = 0; bb < TB; ++bb) {
            float xv = xs[bb][s];
            acc0[bb] = fmaf(xv, w0, acc0[bb]);
            acc1[bb] = fmaf(xv, w1, acc1[bb]);
        }
    }
    float bias0 = b1[t], bias1 = b1[t + 256];
    #pragma unroll
    for (int bb = 0; bb < TB; ++bb) {
        hs[bb][t]       = tanhf(acc0[bb] + bias0);
        hs[bb][t + 256] = tanhf(acc1[bb] + bias1);
    }
    __syncthreads();

    if (m == 0) {
        const float* W2 = eW2;
        const float* b2 = eb2;
        int o  = t & 63;
        int bq = t >> 6;                     // 0..3
        #pragma unroll
        for (int i = 0; i < TB / 4; ++i) {
            int bb = bq + i * 4;
            float acc = b2[o];
            for (int j = 0; j < H_; ++j)
                acc = fmaf(hs[bb][j], W2[(size_t)j * E_ + o], acc);
            e0_out[(size_t)(b0 + bb) * E_ + o] = acc;
        }
    } else {
        const float* W2 = rW2 + (size_t)(m - 1) * H_ * R_;
        const float* b2 = rb2 + (size_t)(m - 1) * R_;
        int o  = t & 31;
        int bb = t >> 5;                     // 0..7 == TB
        float acc = b2[o];
        for (int j = 0; j < H_; ++j)
            acc = fmaf(hs[bb][j], W2[(size_t)j * R_ + o], acc);
        r_out[((size_t)(m - 1) * B_ + (b0 + bb)) * R_ + o] = acc;
    }
}

// ---------------------------------------------------------------------------
// Kernel 2: fused per-b TPR chain, single pass over tpr[b].
//  Phase M: stream tpr[b] (512 KB) once, non-temporal (read-once data):
//    - t0 partial[f] += e0[e] * (sum_r r0[r]*tpr[b,e,r,f])   (regs -> red)
//    - M1[e][f], M2[e][f] into LDS (32 KB)
//  Phase S: wave 0 only (no barriers inside): LN chain + Z projection.
// LDS ~37 KB -> 4 blocks/CU, matching grid 1024 = 4 * 256 CUs.
// ---------------------------------------------------------------------------
__global__ __launch_bounds__(256) void tpr_kernel(
    const float* __restrict__ tpr,   // [B,E,R,E]
    const float* __restrict__ e0,    // [B,E]
    const float* __restrict__ rws,   // [3,B,R]
    const float* __restrict__ ln_g,  // [3,E]
    const float* __restrict__ ln_b,  // [3,E]
    const float* __restrict__ Z,     // [E,L]
    float* __restrict__ out)         // [B,L]
{
    __shared__ __align__(16) float M[2][E_][E_];     // 32 KB  (M1, M2)
    __shared__ __align__(16) float red[16][E_];      // 4 KB   (t0 partials)
    __shared__ float xcur[E_];
    __shared__ float ssum_sh[E_];
    __shared__ float rsh[3][R_];
    __shared__ float e0sh[E_];

    const int t = threadIdx.x;
    const int b = blockIdx.x;

    if (t < 96) { int k = t >> 5, j = t & 31; rsh[k][j] = rws[((size_t)k * B_ + b) * R_ + j]; }
    if (t < E_) e0sh[t] = e0[(size_t)b * E_ + t];
    __syncthreads();

    // ---- Phase M: stream tpr[b] once (float4, non-temporal) ----
    const nfloat4* tpr4 = (const nfloat4*)(tpr + (size_t)b * E_ * R_ * E_);
    const int f4 = t & 15;       // float4 index within the 64-float f row
    const int eg = t >> 4;       // 0..15

    nfloat4 t0p = {0, 0, 0, 0};
    #pragma unroll
    for (int ep = 0; ep < 4; ++ep) {
        int e = eg + 16 * ep;
        nfloat4 a0 = {0, 0, 0, 0}, a1 = {0, 0, 0, 0}, a2 = {0, 0, 0, 0};
        #pragma unroll 16
        for (int r = 0; r < R_; ++r) {
            nfloat4 v = __builtin_nontemporal_load(tpr4 + e * 512 + r * 16 + f4);
            float w0 = rsh[0][r], w1 = rsh[1][r], w2 = rsh[2][r];
            a0.x = fmaf(w0, v.x, a0.x); a0.y = fmaf(w0, v.y, a0.y);
            a0.z = fmaf(w0, v.z, a0.z); a0.w = fmaf(w0, v.w, a0.w);
            a1.x = fmaf(w1, v.x, a1.x); a1.y = fmaf(w1, v.y, a1.y);
            a1.z = fmaf(w1, v.z, a1.z); a1.w = fmaf(w1, v.w, a1.w);
            a2.x = fmaf(w2, v.x, a2.x); a2.y = fmaf(w2, v.y, a2.y);
            a2.z = fmaf(w2, v.z, a2.z); a2.w = fmaf(w2, v.w, a2.w);
        }
        ((nfloat4*)&M[0][e][0])[f4] = a1;
        ((nfloat4*)&M[1][e][0])[f4] = a2;
        float ev = e0sh[e];
        t0p.x = fmaf(ev, a0.x, t0p.x); t0p.y = fmaf(ev, a0.y, t0p.y);
        t0p.z = fmaf(ev, a0.z, t0p.z); t0p.w = fmaf(ev, a0.w, t0p.w);
    }
    ((nfloat4*)&red[eg][0])[f4] = t0p;
    __syncthreads();

    // ---- Phase S: wave 0 only, no barriers (in-wave LDS ordering suffices) ----
    if (t < E_) {
        const int f = t;
        float acc = 0.0f;
        #pragma unroll
        for (int g = 0; g < 16; ++g) acc += red[g][f];

        float ssum = 0.0f;
        #pragma unroll
        for (int k = 0; k < 3; ++k) {
            float s = acc;
            #pragma unroll
            for (int off = 32; off >= 1; off >>= 1) s += __shfl_xor(s, off, 64);
            float mu = s * (1.0f / 64.0f);
            float d = acc - mu;
            float vs = d * d;
            #pragma unroll
            for (int off = 32; off >= 1; off >>= 1) vs += __shfl_xor(vs, off, 64);
            float var = vs * (1.0f / 64.0f);
            float iv = ln_g[k * E_ + f] * d * rsqrtf(var + EPS_) + ln_b[k * E_ + f];
            ssum += iv;
            if (k < 2) {
                xcur[f] = iv;
                float na = 0.0f;
                #pragma unroll 8
                for (int e = 0; e < E_; ++e)
                    na = fmaf(xcur[e], M[k][e][f], na);
                acc = na;
            }
        }
        ssum_sh[f] = ssum;

        if (t < L_) {
            float o = 0.0f;
            #pragma unroll
            for (int f2 = 0; f2 < E_; ++f2)
                o = fmaf(ssum_sh[f2], Z[f2 * L_ + t], o);
            out[(size_t)b * L_ + t] = o;
        }
    }
}

// ---------------------------------------------------------------------------
extern "C" void kernel_launch(void* const* d_in, const int* in_sizes, int n_in,
                              void* d_out, int out_size, void* d_ws, size_t ws_size,
                              hipStream_t stream) {
    const float* x    = (const float*)d_in[0];
    const float* tpr  = (const float*)d_in[1];
    const float* eW1  = (const float*)d_in[2];
    const float* eb1  = (const float*)d_in[3];
    const float* eW2  = (const float*)d_in[4];
    const float* eb2  = (const float*)d_in[5];
    const float* rW1  = (const float*)d_in[6];
    const float* rb1  = (const float*)d_in[7];
    const float* rW2  = (const float*)d_in[8];
    const float* rb2  = (const float*)d_in[9];
    const float* ln_g = (const float*)d_in[10];
    const float* ln_b = (const float*)d_in[11];
    const float* Z    = (const float*)d_in[12];
    float* out = (float*)d_out;

    float* e0_ws = (float*)d_ws;             // B*E floats
    float* r_ws  = e0_ws + (size_t)B_ * E_;  // 3*B*R floats

    dim3 g1(B_ / TB, 4);
    mlp_kernel<<<g1, 256, 0, stream>>>(x, eW1, eb1, eW2, eb2,
                                       rW1, rb1, rW2, rb2, e0_ws, r_ws);
    tpr_kernel<<<B_, 256, 0, stream>>>(tpr, e0_ws, r_ws, ln_g, ln_b, Z, out);
}